// Round 14
// baseline (752.431 us; speedup 1.0000x reference)
//
#include <hip/hip_runtime.h>

#define TT 512
#define NB 128   // batch
#define DD 128
#define HH 64
#define CC 45

__device__ __forceinline__ float sigf(float x) { return 1.0f / (1.0f + __expf(-x)); }

// LDS-only barrier: syncs LDS visibility WITHOUT draining vmcnt (global
// loads/stores stay in flight across steps). Proven worth 75us/rec (R5->R6).
#define LDS_BAR() asm volatile("s_waitcnt lgkmcnt(0)\n\ts_barrier" ::: "memory")

// Quad-lane xor via DPP quad_perm: VALU-speed (~2cy) vs ds_swizzle (~60cy).
#define QP_XOR1(x) __int_as_float(__builtin_amdgcn_mov_dpp(__float_as_int(x), 0xB1, 0xF, 0xF, true))
#define QP_XOR2(x) __int_as_float(__builtin_amdgcn_mov_dpp(__float_as_int(x), 0x4E, 0xF, 0xF, true))

// bf16 helpers (RN rounding), ushort carries the bit pattern.
__device__ __forceinline__ ushort f2bf(float x) {
    uint u = __float_as_uint(x);
    u += 0x7FFFu + ((u >> 16) & 1u);
    return (ushort)(u >> 16);
}
__device__ __forceinline__ float bf2f(ushort h) { return __uint_as_float(((uint)h) << 16); }

typedef short short8 __attribute__((ext_vector_type(8)));
typedef float f32x4 __attribute__((ext_vector_type(4)));

// ---------------------------------------------------------------------------
// GEMM via split-bf16 MFMA (R12, proven).
// ---------------------------------------------------------------------------
__global__ __launch_bounds__(256, 1) void gemm_xz_mfma(
    const float* __restrict__ A, const float* __restrict__ Wf,
    const float* __restrict__ Wb, const float* __restrict__ biasf,
    const float* __restrict__ biasb, float* __restrict__ Cout)
{
    __shared__ ushort Ah[128][136];
    __shared__ ushort Al[128][136];
    __shared__ ushort Wh[128][136];
    __shared__ ushort Wl[128][136];

    const int tid = threadIdx.x;
    const int n0  = blockIdx.x * 128;
    const int m0  = blockIdx.y * 128;
    const float* W   = (n0 < 256) ? Wf : Wb;
    const float* bia = (n0 < 256) ? biasf : biasb;
    const int nc0 = n0 & 255;

    {
        const int r  = tid >> 1;
        const int cb = (tid & 1) * 64;
        #pragma unroll
        for (int i = 0; i < 16; ++i) {
            const int c = cb + i * 4;
            const float4 v = *(const float4*)&A[(size_t)(m0 + r) * 128 + c];
            const ushort hx = f2bf(v.x), hy = f2bf(v.y), hz = f2bf(v.z), hw = f2bf(v.w);
            const ushort lx = f2bf(v.x - bf2f(hx)), ly = f2bf(v.y - bf2f(hy));
            const ushort lz = f2bf(v.z - bf2f(hz)), lw = f2bf(v.w - bf2f(hw));
            *(uint*)&Ah[r][c]     = (uint)hx | ((uint)hy << 16);
            *(uint*)&Ah[r][c + 2] = (uint)hz | ((uint)hw << 16);
            *(uint*)&Al[r][c]     = (uint)lx | ((uint)ly << 16);
            *(uint*)&Al[r][c + 2] = (uint)lz | ((uint)lw << 16);
            const float4 wv = *(const float4*)&W[(size_t)r * 256 + nc0 + c];
            const ushort whx = f2bf(wv.x), why = f2bf(wv.y), whz = f2bf(wv.z), whw = f2bf(wv.w);
            Wh[c + 0][r] = whx; Wl[c + 0][r] = f2bf(wv.x - bf2f(whx));
            Wh[c + 1][r] = why; Wl[c + 1][r] = f2bf(wv.y - bf2f(why));
            Wh[c + 2][r] = whz; Wl[c + 2][r] = f2bf(wv.z - bf2f(whz));
            Wh[c + 3][r] = whw; Wl[c + 3][r] = f2bf(wv.w - bf2f(whw));
        }
    }
    __syncthreads();

    const int lane = tid & 63, wv_ = tid >> 6;
    const int fr = lane & 15, fg = lane >> 4;

    f32x4 acc[2][8];
    #pragma unroll
    for (int ms = 0; ms < 2; ++ms)
        #pragma unroll
        for (int nt = 0; nt < 8; ++nt) acc[ms][nt] = (f32x4){0.f, 0.f, 0.f, 0.f};

    #pragma unroll
    for (int ks = 0; ks < 4; ++ks) {
        const int kb = ks * 32 + fg * 8;
        const short8 ah0 = *(const short8*)&Ah[wv_ * 32 + fr][kb];
        const short8 al0 = *(const short8*)&Al[wv_ * 32 + fr][kb];
        const short8 ah1 = *(const short8*)&Ah[wv_ * 32 + 16 + fr][kb];
        const short8 al1 = *(const short8*)&Al[wv_ * 32 + 16 + fr][kb];
        #pragma unroll
        for (int nt = 0; nt < 8; ++nt) {
            const short8 bh = *(const short8*)&Wh[nt * 16 + fr][kb];
            const short8 bl = *(const short8*)&Wl[nt * 16 + fr][kb];
            acc[0][nt] = __builtin_amdgcn_mfma_f32_16x16x32_bf16(ah0, bh, acc[0][nt], 0, 0, 0);
            acc[0][nt] = __builtin_amdgcn_mfma_f32_16x16x32_bf16(ah0, bl, acc[0][nt], 0, 0, 0);
            acc[0][nt] = __builtin_amdgcn_mfma_f32_16x16x32_bf16(al0, bh, acc[0][nt], 0, 0, 0);
            acc[1][nt] = __builtin_amdgcn_mfma_f32_16x16x32_bf16(ah1, bh, acc[1][nt], 0, 0, 0);
            acc[1][nt] = __builtin_amdgcn_mfma_f32_16x16x32_bf16(ah1, bl, acc[1][nt], 0, 0, 0);
            acc[1][nt] = __builtin_amdgcn_mfma_f32_16x16x32_bf16(al1, bh, acc[1][nt], 0, 0, 0);
        }
    }

    #pragma unroll
    for (int nt = 0; nt < 8; ++nt) {
        const float bb = bia[nc0 + nt * 16 + fr];
        #pragma unroll
        for (int ms = 0; ms < 2; ++ms) {
            #pragma unroll
            for (int j = 0; j < 4; ++j) {
                const int mg = m0 + wv_ * 32 + ms * 16 + fg * 4 + j;
                Cout[(size_t)mg * 512 + n0 + nt * 16 + fr] = acc[ms][nt][j] + bb;
            }
        }
    }
}

// ---------------------------------------------------------------------------
// LSTM recurrence — U stashed in AGPRs (a0..a31).
// R13 post-mortem: the RA will NOT keep 32 U values in VGPRs (pins spill to
// scratch; unpinned loads remat from L2) — 64KB/block/step from L2 at
// ~56B/cyc/CU = ~1170 cyc/step = the 245-254us plateau of every round.
// Fix: v_accvgpr_write a0..a31 once pre-loop (inline asm, clobbered);
// volatile v_accvgpr_read in-loop (~2cy VALU each). Asm-written AGPRs are
// opaque to the RA: not rematerializable, not spillable. No MFMA in this
// kernel, so a0..a31 are free.
// Structure otherwise = R9/R12: 256 blocks x 512 thr; lane bits [1:0]=gate,
// [4:2]=colL, [5]=kh; 32 FMA/lane; K-half reduce via __shfl_xor(32); gate
// gather via 3 DPP quad_perm; ONE LDS_BAR/step; depth-2 xz prefetch;
// fire-and-forget h stores.
// ---------------------------------------------------------------------------
__global__
__attribute__((amdgpu_flat_work_group_size(512, 512), amdgpu_waves_per_eu(1, 2)))
void lstm_rec_ag(
    const float* __restrict__ xz, const float* __restrict__ Uf,
    const float* __restrict__ Ubw, float* __restrict__ hout)
{
    const int b   = blockIdx.x & 127;
    const int dir = blockIdx.x >> 7;
    const int tid = threadIdx.x;
    const int w    = tid >> 6;          // wave 0..7
    const int lane = tid & 63;
    const int gate = lane & 3;          // 0:i 1:f 2:g 3:o (quad -> DPP gather)
    const int colL = (lane >> 2) & 7;
    const int kh   = lane >> 5;         // K-half 0/1
    const int col  = w * 8 + colL;      // h column 0..63
    const int gcol = gate * 64 + col;
    const float* U = dir ? Ubw : Uf;

    __shared__ float hbuf[2][64];

    // Load 32 U values and stash them in AGPRs a0..a31.
    const float* Ug = U + (size_t)(kh * 32) * 256 + gcol;
#define STASH4(A0,A1,A2,A3) { \
    float v0 = Ug[(A0)*256], v1 = Ug[(A1)*256], v2 = Ug[(A2)*256], v3 = Ug[(A3)*256]; \
    asm volatile("v_accvgpr_write_b32 a" #A0 ", %0\n\t" \
                 "v_accvgpr_write_b32 a" #A1 ", %1\n\t" \
                 "v_accvgpr_write_b32 a" #A2 ", %2\n\t" \
                 "v_accvgpr_write_b32 a" #A3 ", %3" \
                 :: "v"(v0), "v"(v1), "v"(v2), "v"(v3) \
                 : "a" #A0, "a" #A1, "a" #A2, "a" #A3); }
    STASH4(0,1,2,3)     STASH4(4,5,6,7)     STASH4(8,9,10,11)
    STASH4(12,13,14,15) STASH4(16,17,18,19) STASH4(20,21,22,23)
    STASH4(24,25,26,27) STASH4(28,29,30,31)
#undef STASH4

    if (tid < 64) hbuf[0][tid] = 0.f;
    float c = 0.f;
    __syncthreads();

    const float* xzb = xz + (size_t)b * TT * 512 + (size_t)dir * 256 + gcol;
    float*       hob = hout + (size_t)b * TT * 128 + (size_t)dir * 64 + col;

    int trow = dir ? (TT - 1) : 0;
    const int ts = dir ? -1 : 1;
    float xc = xzb[(size_t)trow * 512];            // step s
    float x1 = xzb[(size_t)(trow + ts) * 512];     // step s+1

    for (int s = 0; s < TT; ++s) {
        const int p = s & 1;
        float x2 = 0.f;
        if (s + 2 < TT) x2 = xzb[(size_t)(trow + 2 * ts) * 512];  // depth-2

        float s0 = 0.f, s1 = 0.f, s2 = 0.f, s3 = 0.f;
        // Per 4-chunk: volatile AGPR reads (storage = AGPR, re-read each
        // iteration by design) + FMA with broadcast LDS h.
#define ACC(J, A0,A1,A2,A3) { \
        const float4 hv = *(const float4*)&hbuf[p][kh*32 + 4*(J)]; \
        float t0, t1, t2, t3; \
        asm volatile("v_accvgpr_read_b32 %0, a" #A0 "\n\t" \
                     "v_accvgpr_read_b32 %1, a" #A1 "\n\t" \
                     "v_accvgpr_read_b32 %2, a" #A2 "\n\t" \
                     "v_accvgpr_read_b32 %3, a" #A3 \
                     : "=v"(t0), "=v"(t1), "=v"(t2), "=v"(t3)); \
        s0 = __fmaf_rn(hv.x, t0, s0); s1 = __fmaf_rn(hv.y, t1, s1); \
        s2 = __fmaf_rn(hv.z, t2, s2); s3 = __fmaf_rn(hv.w, t3, s3); }
        ACC(0, 0,1,2,3)     ACC(1, 4,5,6,7)     ACC(2, 8,9,10,11)
        ACC(3, 12,13,14,15) ACC(4, 16,17,18,19) ACC(5, 20,21,22,23)
        ACC(6, 24,25,26,27) ACC(7, 28,29,30,31)
#undef ACC
        float part = (s0 + s1) + (s2 + s3);

        part += __shfl_xor(part, 32);
        const float z = xc + part;

        const float a = (gate == 2) ? fmaxf(z, 0.f) : sigf(z);

        const float b0 = QP_XOR1(a);
        const float b1 = QP_XOR2(a);
        const float b2 = QP_XOR2(b0);
        const float ai = (gate == 0) ? a : (gate == 1) ? b0 : (gate == 2) ? b1 : b2;
        const float af = (gate == 1) ? a : (gate == 0) ? b0 : (gate == 3) ? b1 : b2;
        const float ag = (gate == 2) ? a : (gate == 3) ? b0 : (gate == 0) ? b1 : b2;
        const float ao = (gate == 3) ? a : (gate == 2) ? b0 : (gate == 1) ? b1 : b2;

        c = af * c + ai * ag;
        const float h = ao * fmaxf(c, 0.f);

        if ((lane & 0x23) == 0) {           // writer: gate==0 && kh==0
            hbuf[p ^ 1][col] = h;
            hob[(size_t)trow * 128] = h;    // fire-and-forget, never drained
        }

        LDS_BAR();                          // ONE barrier/step; WAR safe (parity)

        xc = x1; x1 = x2;
        trow += ts;
    }
}

// ---------------------------------------------------------------------------
// Dense + softmax: out[m][c] = softmax_c( h2[m][:] @ Wd[:,c] + bd[c] )
// ---------------------------------------------------------------------------
__global__ __launch_bounds__(256) void dense_softmax(
    const float* __restrict__ h2, const float* __restrict__ Wd,
    const float* __restrict__ bd, float* __restrict__ out)
{
    __shared__ float Wl[128 * 45];
    __shared__ float bl[48];
    __shared__ float hrow[4][128];
    const int tid = threadIdx.x;
    for (int i = tid; i < 128 * 45; i += 256) Wl[i] = Wd[i];
    if (tid < 45) bl[tid] = bd[tid];
    __syncthreads();

    const int w = tid >> 6, l = tid & 63;
    const size_t row0 = (size_t)blockIdx.x * 64;
    for (int rr = 0; rr < 16; ++rr) {
        const size_t m = row0 + (size_t)rr * 4 + w;
        const float2 hv = *(const float2*)&h2[m * 128 + l * 2];
        hrow[w][l * 2] = hv.x;
        hrow[w][l * 2 + 1] = hv.y;
        __syncthreads();
        float lg = -3.0e38f;
        if (l < CC) {
            lg = bl[l];
            #pragma unroll 8
            for (int k = 0; k < 128; ++k) lg = __fmaf_rn(hrow[w][k], Wl[k * 45 + l], lg);
        }
        float mx = lg;
        #pragma unroll
        for (int off = 32; off >= 1; off >>= 1) mx = fmaxf(mx, __shfl_xor(mx, off));
        const float e = (l < CC) ? __expf(lg - mx) : 0.f;
        float sm = e;
        #pragma unroll
        for (int off = 32; off >= 1; off >>= 1) sm += __shfl_xor(sm, off);
        if (l < CC) out[m * 45 + l] = e / sm;
        __syncthreads();
    }
}

// ---------------------------------------------------------------------------
extern "C" void kernel_launch(void* const* d_in, const int* in_sizes, int n_in,
                              void* d_out, int out_size, void* d_ws, size_t ws_size,
                              hipStream_t stream)
{
    const float* x   = (const float*)d_in[0];
    const float* W1f = (const float*)d_in[1];
    const float* U1f = (const float*)d_in[2];
    const float* b1f = (const float*)d_in[3];
    const float* W1b = (const float*)d_in[4];
    const float* U1b = (const float*)d_in[5];
    const float* b1b = (const float*)d_in[6];
    const float* W2f = (const float*)d_in[7];
    const float* U2f = (const float*)d_in[8];
    const float* b2f = (const float*)d_in[9];
    const float* W2b = (const float*)d_in[10];
    const float* U2b = (const float*)d_in[11];
    const float* b2b = (const float*)d_in[12];
    const float* Wd  = (const float*)d_in[13];
    const float* bd  = (const float*)d_in[14];

    // Workspace layout (160 MiB):
    //   xz : 65536 x 512 f32 = 128 MiB   (reused by layer 1 and layer 2)
    //   h  : 65536 x 128 f32 =  32 MiB   (h1, then overwritten by h2)
    float* xz = (float*)d_ws;
    float* h  = (float*)((char*)d_ws + (size_t)65536 * 512 * 4);

    const dim3 gemm_grid(4, 512);      // n-tile FASTEST (A-tile L2 sharing)
    const dim3 rec_grid(256);          // 128 batch x 2 directions
    const dim3 dense_grid(1024);       // 65536/64 rows

    // Layer 1
    gemm_xz_mfma<<<gemm_grid, dim3(256), 0, stream>>>(x, W1f, W1b, b1f, b1b, xz);
    lstm_rec_ag<<<rec_grid, dim3(512), 0, stream>>>(xz, U1f, U1b, h);
    // Layer 2
    gemm_xz_mfma<<<gemm_grid, dim3(256), 0, stream>>>(h, W2f, W2b, b2f, b2b, xz);
    lstm_rec_ag<<<rec_grid, dim3(512), 0, stream>>>(xz, U2f, U2b, h);
    // Head
    dense_softmax<<<dense_grid, dim3(256), 0, stream>>>(h, Wd, bd, (float*)d_out);
}

// Round 15
// 602.919 us; speedup vs baseline: 1.2480x; 1.2480x over previous
//
#include <hip/hip_runtime.h>

#define TT 512
#define NB 128   // batch
#define DD 128
#define HH 64
#define CC 45

__device__ __forceinline__ float sigf(float x) { return 1.0f / (1.0f + __expf(-x)); }

// LDS-only barrier: syncs LDS visibility WITHOUT draining vmcnt (global
// loads/stores stay in flight across steps). Proven worth 75us/rec (R5->R6).
#define LDS_BAR() asm volatile("s_waitcnt lgkmcnt(0)\n\ts_barrier" ::: "memory")

// Quad-lane xor via DPP quad_perm: VALU-speed (~2cy) vs ds_swizzle (~60cy).
#define QP_XOR1(x) __int_as_float(__builtin_amdgcn_mov_dpp(__float_as_int(x), 0xB1, 0xF, 0xF, true))
#define QP_XOR2(x) __int_as_float(__builtin_amdgcn_mov_dpp(__float_as_int(x), 0x4E, 0xF, 0xF, true))

// bf16 helpers. f2bf = round-to-nearest; trunc split: hi = top 16 bits
// (free), residual a - hi is exact in f32, lo = RN(residual) -> total
// representation error ~2^-17 relative, same as double-RN split.
__device__ __forceinline__ ushort f2bf(float x) {
    uint u = __float_as_uint(x);
    u += 0x7FFFu + ((u >> 16) & 1u);
    return (ushort)(u >> 16);
}
__device__ __forceinline__ float bf2f(ushort h) { return __uint_as_float(((uint)h) << 16); }

typedef short short8 __attribute__((ext_vector_type(8)));
typedef float f32x4 __attribute__((ext_vector_type(4)));

// ---------------------------------------------------------------------------
// GEMM v2 via split-bf16 MFMA.
// Changes vs R12 (67us): A-fragments loaded DIRECTLY from global (L2-hot;
// A-frag = 8 consecutive k-floats per lane) and trunc-split in registers —
// no A-LDS, no A staging pass. W staged in LDS (transposed [n][k]) with
// trunc-split (hi = top-16-bits, lo = RN(exact residual)): ~half the
// conversion VALU. LDS 136KB -> 68KB => 2 blocks/CU: next block's staging
// overlaps this block's MFMA.
// ---------------------------------------------------------------------------
__global__ __launch_bounds__(256, 2) void gemm_xz_mfma2(
    const float* __restrict__ A, const float* __restrict__ Wf,
    const float* __restrict__ Wb, const float* __restrict__ biasf,
    const float* __restrict__ biasb, float* __restrict__ Cout)
{
    __shared__ ushort Wh[128][136];   // [n][k], pad 136 (272B row stride)
    __shared__ ushort Wl[128][136];

    const int tid = threadIdx.x;
    const int n0  = blockIdx.x * 128;
    const int m0  = blockIdx.y * 128;
    const float* W   = (n0 < 256) ? Wf : Wb;
    const float* bia = (n0 < 256) ? biasf : biasb;
    const int nc0 = n0 & 255;

    // ---- stage W -> Wh/Wl (transposed), trunc-split ----
    {
        const int r  = tid >> 1;                // k row 0..127
        const int cb = (tid & 1) * 64;          // n half
        #pragma unroll
        for (int i = 0; i < 16; ++i) {
            const int c = cb + i * 4;
            const float4 wv = *(const float4*)&W[(size_t)r * 256 + nc0 + c];
            const ushort h0 = (ushort)(__float_as_uint(wv.x) >> 16);
            const ushort h1 = (ushort)(__float_as_uint(wv.y) >> 16);
            const ushort h2 = (ushort)(__float_as_uint(wv.z) >> 16);
            const ushort h3 = (ushort)(__float_as_uint(wv.w) >> 16);
            Wh[c + 0][r] = h0; Wl[c + 0][r] = f2bf(wv.x - bf2f(h0));
            Wh[c + 1][r] = h1; Wl[c + 1][r] = f2bf(wv.y - bf2f(h1));
            Wh[c + 2][r] = h2; Wl[c + 2][r] = f2bf(wv.z - bf2f(h2));
            Wh[c + 3][r] = h3; Wl[c + 3][r] = f2bf(wv.w - bf2f(h3));
        }
    }
    __syncthreads();

    // ---- compute ----
    const int lane = tid & 63, wv_ = tid >> 6;
    const int fr = lane & 15, fg = lane >> 4;

    f32x4 acc[2][8];
    #pragma unroll
    for (int ms = 0; ms < 2; ++ms)
        #pragma unroll
        for (int nt = 0; nt < 8; ++nt) acc[ms][nt] = (f32x4){0.f, 0.f, 0.f, 0.f};

    #pragma unroll
    for (int ks = 0; ks < 4; ++ks) {
        const int kb = ks * 32 + fg * 8;
        // A-fragments straight from global (rows m0+wv_*32+{fr, 16+fr}),
        // trunc-split in registers.
        short8 ah[2], al[2];
        #pragma unroll
        for (int ms = 0; ms < 2; ++ms) {
            const float* ap = &A[(size_t)(m0 + wv_ * 32 + ms * 16 + fr) * 128 + kb];
            const float4 va = *(const float4*)ap;
            const float4 vb = *(const float4*)(ap + 4);
            float v[8] = {va.x, va.y, va.z, va.w, vb.x, vb.y, vb.z, vb.w};
            #pragma unroll
            for (int j = 0; j < 8; ++j) {
                const ushort hj = (ushort)(__float_as_uint(v[j]) >> 16);
                ah[ms][j] = (short)hj;
                al[ms][j] = (short)f2bf(v[j] - bf2f(hj));
            }
        }
        #pragma unroll
        for (int nt = 0; nt < 8; ++nt) {
            const short8 bh = *(const short8*)&Wh[nt * 16 + fr][kb];
            const short8 bl = *(const short8*)&Wl[nt * 16 + fr][kb];
            acc[0][nt] = __builtin_amdgcn_mfma_f32_16x16x32_bf16(ah[0], bh, acc[0][nt], 0, 0, 0);
            acc[0][nt] = __builtin_amdgcn_mfma_f32_16x16x32_bf16(ah[0], bl, acc[0][nt], 0, 0, 0);
            acc[0][nt] = __builtin_amdgcn_mfma_f32_16x16x32_bf16(al[0], bh, acc[0][nt], 0, 0, 0);
            acc[1][nt] = __builtin_amdgcn_mfma_f32_16x16x32_bf16(ah[1], bh, acc[1][nt], 0, 0, 0);
            acc[1][nt] = __builtin_amdgcn_mfma_f32_16x16x32_bf16(ah[1], bl, acc[1][nt], 0, 0, 0);
            acc[1][nt] = __builtin_amdgcn_mfma_f32_16x16x32_bf16(al[1], bh, acc[1][nt], 0, 0, 0);
        }
    }

    // ---- store (+bias); C/D layout: col=lane&15, row=(lane>>4)*4+j ----
    #pragma unroll
    for (int nt = 0; nt < 8; ++nt) {
        const float bb = bia[nc0 + nt * 16 + fr];
        #pragma unroll
        for (int ms = 0; ms < 2; ++ms) {
            #pragma unroll
            for (int j = 0; j < 4; ++j) {
                const int mg = m0 + wv_ * 32 + ms * 16 + fg * 4 + j;
                Cout[(size_t)mg * 512 + n0 + nt * 16 + fr] = acc[ms][nt][j] + bb;
            }
        }
    }
}

// ---------------------------------------------------------------------------
// LSTM recurrence (R12 exact — best measured: 245.2us/dispatch, absmax
// 2.44e-4). 256 blocks (batch x dir) x 512 threads. Lane bits: [1:0]=gate,
// [4:2]=colL, [5]=kh. Wave owns 8 cols; 32 U loads (L2-resident re-fetch is
// this structure's cost of doing business — R14 proved removing it via AGPR
// costs MORE in issue); 32 FMA; K-half reduce via __shfl_xor(32); gate
// gather via 3 DPP quad_perm; ONE LDS_BAR/step; depth-2 xz prefetch.
// ---------------------------------------------------------------------------
__global__
__attribute__((amdgpu_flat_work_group_size(512, 512), amdgpu_waves_per_eu(1, 2)))
void lstm_rec_qp(
    const float* __restrict__ xz, const float* __restrict__ Uf,
    const float* __restrict__ Ubw, float* __restrict__ hout)
{
    const int b   = blockIdx.x & 127;
    const int dir = blockIdx.x >> 7;
    const int tid = threadIdx.x;
    const int w    = tid >> 6;          // wave 0..7
    const int lane = tid & 63;
    const int gate = lane & 3;          // 0:i 1:f 2:g 3:o (quad -> DPP gather)
    const int colL = (lane >> 2) & 7;
    const int kh   = lane >> 5;         // K-half 0/1
    const int col  = w * 8 + colL;      // h column 0..63
    const int gcol = gate * 64 + col;
    const float* U = dir ? Ubw : Uf;

    __shared__ float hbuf[2][64];

    const float* Ug = U + (size_t)(kh * 32) * 256 + gcol;
    float u0  = Ug[ 0*256], u1  = Ug[ 1*256], u2  = Ug[ 2*256], u3  = Ug[ 3*256];
    float u4  = Ug[ 4*256], u5  = Ug[ 5*256], u6  = Ug[ 6*256], u7  = Ug[ 7*256];
    float u8  = Ug[ 8*256], u9  = Ug[ 9*256], u10 = Ug[10*256], u11 = Ug[11*256];
    float u12 = Ug[12*256], u13 = Ug[13*256], u14 = Ug[14*256], u15 = Ug[15*256];
    float u16 = Ug[16*256], u17 = Ug[17*256], u18 = Ug[18*256], u19 = Ug[19*256];
    float u20 = Ug[20*256], u21 = Ug[21*256], u22 = Ug[22*256], u23 = Ug[23*256];
    float u24 = Ug[24*256], u25 = Ug[25*256], u26 = Ug[26*256], u27 = Ug[27*256];
    float u28 = Ug[28*256], u29 = Ug[29*256], u30 = Ug[30*256], u31 = Ug[31*256];
    asm volatile("" : "+v"(u0),"+v"(u1),"+v"(u2),"+v"(u3),
                      "+v"(u4),"+v"(u5),"+v"(u6),"+v"(u7));
    asm volatile("" : "+v"(u8),"+v"(u9),"+v"(u10),"+v"(u11),
                      "+v"(u12),"+v"(u13),"+v"(u14),"+v"(u15));
    asm volatile("" : "+v"(u16),"+v"(u17),"+v"(u18),"+v"(u19),
                      "+v"(u20),"+v"(u21),"+v"(u22),"+v"(u23));
    asm volatile("" : "+v"(u24),"+v"(u25),"+v"(u26),"+v"(u27),
                      "+v"(u28),"+v"(u29),"+v"(u30),"+v"(u31));

    if (tid < 64) hbuf[0][tid] = 0.f;
    float c = 0.f;
    __syncthreads();

    const float* xzb = xz + (size_t)b * TT * 512 + (size_t)dir * 256 + gcol;
    float*       hob = hout + (size_t)b * TT * 128 + (size_t)dir * 64 + col;

    int trow = dir ? (TT - 1) : 0;
    const int ts = dir ? -1 : 1;
    float xc = xzb[(size_t)trow * 512];            // step s
    float x1 = xzb[(size_t)(trow + ts) * 512];     // step s+1

    for (int s = 0; s < TT; ++s) {
        const int p = s & 1;
        float x2 = 0.f;
        if (s + 2 < TT) x2 = xzb[(size_t)(trow + 2 * ts) * 512];  // depth-2

        float a0 = 0.f, a1 = 0.f, a2 = 0.f, a3 = 0.f;
#define ACC(J, A,B,C,D) { const float4 hv = *(const float4*)&hbuf[p][kh*32 + 4*(J)]; \
        a0 = __fmaf_rn(hv.x, A, a0); a1 = __fmaf_rn(hv.y, B, a1); \
        a2 = __fmaf_rn(hv.z, C, a2); a3 = __fmaf_rn(hv.w, D, a3); }
        ACC(0,u0 ,u1 ,u2 ,u3 ) ACC(1,u4 ,u5 ,u6 ,u7 )
        ACC(2,u8 ,u9 ,u10,u11) ACC(3,u12,u13,u14,u15)
        ACC(4,u16,u17,u18,u19) ACC(5,u20,u21,u22,u23)
        ACC(6,u24,u25,u26,u27) ACC(7,u28,u29,u30,u31)
#undef ACC
        float part = (a0 + a1) + (a2 + a3);

        part += __shfl_xor(part, 32);
        const float z = xc + part;

        const float a = (gate == 2) ? fmaxf(z, 0.f) : sigf(z);

        const float b0 = QP_XOR1(a);
        const float b1 = QP_XOR2(a);
        const float b2 = QP_XOR2(b0);
        const float ai = (gate == 0) ? a : (gate == 1) ? b0 : (gate == 2) ? b1 : b2;
        const float af = (gate == 1) ? a : (gate == 0) ? b0 : (gate == 3) ? b1 : b2;
        const float ag = (gate == 2) ? a : (gate == 3) ? b0 : (gate == 0) ? b1 : b2;
        const float ao = (gate == 3) ? a : (gate == 2) ? b0 : (gate == 1) ? b1 : b2;

        c = af * c + ai * ag;
        const float h = ao * fmaxf(c, 0.f);

        if ((lane & 0x23) == 0) {           // writer: gate==0 && kh==0
            hbuf[p ^ 1][col] = h;
            hob[(size_t)trow * 128] = h;    // fire-and-forget, never drained
        }

        LDS_BAR();                          // ONE barrier/step; WAR safe (parity)

        xc = x1; x1 = x2;
        trow += ts;
    }
}

// ---------------------------------------------------------------------------
// Dense + softmax: out[m][c] = softmax_c( h2[m][:] @ Wd[:,c] + bd[c] )
// ---------------------------------------------------------------------------
__global__ __launch_bounds__(256) void dense_softmax(
    const float* __restrict__ h2, const float* __restrict__ Wd,
    const float* __restrict__ bd, float* __restrict__ out)
{
    __shared__ float Wl[128 * 45];
    __shared__ float bl[48];
    __shared__ float hrow[4][128];
    const int tid = threadIdx.x;
    for (int i = tid; i < 128 * 45; i += 256) Wl[i] = Wd[i];
    if (tid < 45) bl[tid] = bd[tid];
    __syncthreads();

    const int w = tid >> 6, l = tid & 63;
    const size_t row0 = (size_t)blockIdx.x * 64;
    for (int rr = 0; rr < 16; ++rr) {
        const size_t m = row0 + (size_t)rr * 4 + w;
        const float2 hv = *(const float2*)&h2[m * 128 + l * 2];
        hrow[w][l * 2] = hv.x;
        hrow[w][l * 2 + 1] = hv.y;
        __syncthreads();
        float lg = -3.0e38f;
        if (l < CC) {
            lg = bl[l];
            #pragma unroll 8
            for (int k = 0; k < 128; ++k) lg = __fmaf_rn(hrow[w][k], Wl[k * 45 + l], lg);
        }
        float mx = lg;
        #pragma unroll
        for (int off = 32; off >= 1; off >>= 1) mx = fmaxf(mx, __shfl_xor(mx, off));
        const float e = (l < CC) ? __expf(lg - mx) : 0.f;
        float sm = e;
        #pragma unroll
        for (int off = 32; off >= 1; off >>= 1) sm += __shfl_xor(sm, off);
        if (l < CC) out[m * 45 + l] = e / sm;
        __syncthreads();
    }
}

// ---------------------------------------------------------------------------
extern "C" void kernel_launch(void* const* d_in, const int* in_sizes, int n_in,
                              void* d_out, int out_size, void* d_ws, size_t ws_size,
                              hipStream_t stream)
{
    const float* x   = (const float*)d_in[0];
    const float* W1f = (const float*)d_in[1];
    const float* U1f = (const float*)d_in[2];
    const float* b1f = (const float*)d_in[3];
    const float* W1b = (const float*)d_in[4];
    const float* U1b = (const float*)d_in[5];
    const float* b1b = (const float*)d_in[6];
    const float* W2f = (const float*)d_in[7];
    const float* U2f = (const float*)d_in[8];
    const float* b2f = (const float*)d_in[9];
    const float* W2b = (const float*)d_in[10];
    const float* U2b = (const float*)d_in[11];
    const float* b2b = (const float*)d_in[12];
    const float* Wd  = (const float*)d_in[13];
    const float* bd  = (const float*)d_in[14];

    // Workspace layout (160 MiB):
    //   xz : 65536 x 512 f32 = 128 MiB   (reused by layer 1 and layer 2)
    //   h  : 65536 x 128 f32 =  32 MiB   (h1, then overwritten by h2)
    float* xz = (float*)d_ws;
    float* h  = (float*)((char*)d_ws + (size_t)65536 * 512 * 4);

    const dim3 gemm_grid(4, 512);      // n-tile FASTEST (A-tile L2 sharing)
    const dim3 rec_grid(256);          // 128 batch x 2 directions
    const dim3 dense_grid(1024);       // 65536/64 rows

    // Layer 1
    gemm_xz_mfma2<<<gemm_grid, dim3(256), 0, stream>>>(x, W1f, W1b, b1f, b1b, xz);
    lstm_rec_qp<<<rec_grid, dim3(512), 0, stream>>>(xz, U1f, U1b, h);
    // Layer 2
    gemm_xz_mfma2<<<gemm_grid, dim3(256), 0, stream>>>(h, W2f, W2b, b2f, b2b, xz);
    lstm_rec_qp<<<rec_grid, dim3(512), 0, stream>>>(xz, U2f, U2b, h);
    // Head
    dense_softmax<<<dense_grid, dim3(256), 0, stream>>>(h, Wd, bd, (float*)d_out);
}